// Round 5
// baseline (320.731 us; speedup 1.0000x reference)
//
#include <hip/hip_runtime.h>
#include <hip/hip_bf16.h>

#define B_  16
#define S_  4096
#define DIN 512
#define DH  512

typedef _Float16 f16x8 __attribute__((ext_vector_type(8)));
typedef float    f32x4 __attribute__((ext_vector_type(4)));

// ---------------- ws layout (bytes) ----------------
// W16     : [DH][DIN] fp16      @ 0        (524288)
// addv    : [B_][DH]  f32       @ 524288   (32768)   = input@W_in.T + b_in + b_ctx
// scores  : [B_][S_]  f32       @ 557056   (262144)  zeroed in prep, atomicAdd by score
// wsum    : [B_][DIN] f32       @ 819200   (32768)   zeroed in prep, atomicAdd by attnwsum
// maskflag: int                 @ 851968   (4)

__device__ __forceinline__ float fast_tanh(float x) {
    float e = __expf(2.f * x);
    return 1.f - 2.f * __builtin_amdgcn_rcpf(e + 1.f);
}

__device__ __forceinline__ void gload_lds16(const void* g, void* l) {
    __builtin_amdgcn_global_load_lds(
        (const __attribute__((address_space(1))) void*)g,
        (__attribute__((address_space(3))) void*)l, 16, 0, 0);
}

__device__ __forceinline__ int mask_at(const void* mask, int isByte, int idx) {
    return isByte ? (int)((const unsigned char*)mask)[idx]
                  : ((const int*)mask)[idx];
}

// ---------------- prep ----------------
// grid 307:
//   [0,256)   W_ctx f32 -> f16
//   [256,288) addv = input@W_in.T + b_in + b_ctx
//   288       mask dtype detect
//   [289,307) zero scores (65536 f) + wsum (8192 f) = 73728 f = 18 blk * 4096
__global__ __launch_bounds__(256)
void prep_kernel(const float* __restrict__ input,
                 const float* __restrict__ W_in,
                 const float* __restrict__ b_in,
                 const float* __restrict__ W_ctx,
                 const float* __restrict__ b_ctx,
                 const void*  __restrict__ mask,
                 _Float16* __restrict__ W16,
                 float* __restrict__ addv,
                 float* __restrict__ zeroRegion,
                 int* __restrict__ maskflag) {
    int blk = blockIdx.x;
    int tid = threadIdx.x;
    if (blk < 256) {
        int base = blk * 1024 + tid * 4;
        float4 wv = *(const float4*)(W_ctx + base);
        union { _Float16 f[4]; ushort4 u; } cv;
        cv.f[0] = (_Float16)wv.x; cv.f[1] = (_Float16)wv.y;
        cv.f[2] = (_Float16)wv.z; cv.f[3] = (_Float16)wv.w;
        *(ushort4*)(W16 + base) = cv.u;
    } else if (blk < 288) {
        int t = blk - 256;
        int b = t >> 1;
        int h = ((t & 1) << 8) + tid;
        __shared__ float inrow[DIN];
        inrow[tid]       = input[b * DIN + tid];
        inrow[tid + 256] = input[b * DIN + tid + 256];
        __syncthreads();
        const float* wr = W_in + (size_t)h * DIN;
        float acc = 0.f;
        for (int k = 0; k < DIN; k += 4) {
            float4 w4 = *(const float4*)(wr + k);
            acc += w4.x * inrow[k] + w4.y * inrow[k + 1]
                 + w4.z * inrow[k + 2] + w4.w * inrow[k + 3];
        }
        addv[b * DH + h] = acc + b_in[h] + b_ctx[h];
    } else if (blk == 288) {
        const uint4* m4 = (const uint4*)mask;
        unsigned int orw = 0;
#pragma unroll
        for (int it = 0; it < 16; ++it) {
            uint4 w = m4[it * 256 + tid];
            orw |= (w.x | w.y | w.z | w.w);
        }
        int found = ((orw & 0xFFFFFF00u) != 0) ? 1 : 0;
        __shared__ int f;
        if (tid == 0) f = 0;
        __syncthreads();
        if (found) atomicOr(&f, 1);
        __syncthreads();
        if (tid == 0) maskflag[0] = f;
    } else {
        int base = (blk - 289) * 4096;
#pragma unroll
        for (int it = 0; it < 16; ++it)
            zeroRegion[base + it * 256 + tid] = 0.f;
    }
}

// ---------------- score GEMM: partial rowsum of v.tanh(addv + ctx@W16^T) ----
// r4 structure (fused cvt, linear A-staging, 2-deep named lookahead) with the
// per-K-step __syncthreads() replaced by COUNTED vmcnt + raw s_barrier (T4):
//   issue order pinned: STAGE_B (2 gload_lds, oldest) -> LOADA (4 global, newest)
//   step end: s_waitcnt vmcnt(4) retires exactly the 2 gload_lds (FIFO), the 4
//   A-loads for kc+2 stay in flight ACROSS the barrier -> full-step HBM cover.
//   WRITEA's dependence on LOADA(kc+1) gets an automatic vmcnt(6) from dataflow.
__global__ __launch_bounds__(256, 3)
void score_kernel(const float* __restrict__ context,
                  const _Float16* __restrict__ W16,
                  const float* __restrict__ addv,
                  const float* __restrict__ v,
                  float* __restrict__ scores) {
    __shared__ __align__(16) _Float16 As[2][4096];   // 8KB/buf: 8 m-tiles x 512 halves
    __shared__ __align__(16) _Float16 Bs[2][4096];   // 8KB/buf: 8 n-tiles x 512 halves

    const int tid  = threadIdx.x;
    const int wave = tid >> 6;
    const int lane = tid & 63;
    const int l15  = lane & 15;
    const int q    = lane >> 4;
    const int sg   = wave >> 1;        // 0..1 : s-group (64 rows)
    const int ng   = wave & 1;         // 0..1 : n-group (64 cols)

    const int xcd  = blockIdx.x & 7;
    const int slot = blockIdx.x >> 3;          // 0..255
    const int nt   = slot & 3;
    const int g    = (slot >> 2) * 8 + xcd;    // 0..511
    const int b    = g >> 5;
    const int st   = g & 31;
    const int s0   = st * 128;
    const int n0   = nt * 128;

    const float* ctxA = context + ((size_t)b * S_ + s0) * DIN;

    // A ownership: ids id0=tid, id1=tid+256 -> rows (id>>6)*16+(id&15),
    // k-base ((id>>4)&3)*8. Write f16x8 at halves id*8 (linear, 0 conflicts).
    const int rowA0 = ((tid >> 6) * 16) + (tid & 15);
    const int kbA0  = ((tid >> 4) & 3) * 8;
    const int rowA1 = rowA0 + 64;

#define STAGE_B(kc_, buf_)                                                     \
    {                                                                          \
        _Pragma("unroll")                                                      \
        for (int u = 0; u < 2; ++u) {                                          \
            int jn = wave * 2 + u;                                             \
            const _Float16* gp = W16 +                                         \
                (size_t)(n0 + jn * 16 + l15) * DIN + (kc_) * 32 + q * 8;       \
            gload_lds16(gp, &Bs[buf_][jn * 512]);                              \
        }                                                                      \
    }

#define LOADA(kc_, set_)                                                       \
    {                                                                          \
        const float* g0 = ctxA + (size_t)rowA0 * DIN + (kc_) * 32 + kbA0;      \
        const float* g1 = ctxA + (size_t)rowA1 * DIN + (kc_) * 32 + kbA0;      \
        set_[0] = *(const float4*)g0; set_[1] = *(const float4*)(g0 + 4);      \
        set_[2] = *(const float4*)g1; set_[3] = *(const float4*)(g1 + 4);      \
    }

#define WRITEA(set_, buf_)                                                     \
    {                                                                          \
        f16x8 h0, h1;                                                          \
        h0[0] = (_Float16)set_[0].x; h0[1] = (_Float16)set_[0].y;              \
        h0[2] = (_Float16)set_[0].z; h0[3] = (_Float16)set_[0].w;              \
        h0[4] = (_Float16)set_[1].x; h0[5] = (_Float16)set_[1].y;              \
        h0[6] = (_Float16)set_[1].z; h0[7] = (_Float16)set_[1].w;              \
        h1[0] = (_Float16)set_[2].x; h1[1] = (_Float16)set_[2].y;              \
        h1[2] = (_Float16)set_[2].z; h1[3] = (_Float16)set_[2].w;              \
        h1[4] = (_Float16)set_[3].x; h1[5] = (_Float16)set_[3].y;              \
        h1[6] = (_Float16)set_[3].z; h1[7] = (_Float16)set_[3].w;              \
        *(f16x8*)&As[buf_][tid * 8]        = h0;                               \
        *(f16x8*)&As[buf_][tid * 8 + 2048] = h1;                               \
    }

    f32x4 acc[4][4];
#pragma unroll
    for (int jm = 0; jm < 4; ++jm)
#pragma unroll
        for (int jn = 0; jn < 4; ++jn) acc[jm][jn] = (f32x4){0.f, 0.f, 0.f, 0.f};

    float4 aA[4], aB[4];   // two named lookahead sets

    // prologue: B(0) then A(0) (FIFO: B oldest); WRITEA auto-drains; A(1) stays
    // in flight across the first barrier.
    STAGE_B(0, 0);
    __builtin_amdgcn_sched_barrier(0);
    LOADA(0, aA);
    WRITEA(aA, 0);                      // compiler waits for A(0) (drains B(0) too)
    LOADA(1, aB);
    asm volatile("s_waitcnt lgkmcnt(0)" ::: "memory");
    __builtin_amdgcn_s_barrier();

    // steady state per step kc (outstanding at entry: LOADA(kc+1) x4):
    //   STAGE_B(kc+1) [2 vm, issued first] | sched_barrier | LOADA(kc+2) [4 vm]
    //   ds_read frags(buf kc) -> MFMA x16 -> WRITEA(kc+1 data, auto vmcnt(6))
    //   s_waitcnt vmcnt(4) (retires B(kc+1); A(kc+2) survives) + lgkmcnt(0)
    //   raw s_barrier
#define STEP(kc_, buf_, ldset_, wrset_)                                        \
    {                                                                          \
        if ((kc_) + 1 < 16) STAGE_B((kc_) + 1, (buf_) ^ 1);                    \
        __builtin_amdgcn_sched_barrier(0);                                     \
        if ((kc_) + 2 < 16) LOADA((kc_) + 2, ldset_);                          \
        f16x8 afr[4], bfr[4];                                                  \
        _Pragma("unroll")                                                      \
        for (int jm = 0; jm < 4; ++jm)                                         \
            afr[jm] = *(const f16x8*)&As[buf_][(sg * 4 + jm) * 512 +           \
                                              q * 128 + l15 * 8];              \
        _Pragma("unroll")                                                      \
        for (int jn = 0; jn < 4; ++jn)                                         \
            bfr[jn] = *(const f16x8*)&Bs[buf_][(ng * 4 + jn) * 512 +           \
                                              q * 128 + l15 * 8];              \
        _Pragma("unroll")                                                      \
        for (int jn = 0; jn < 4; ++jn)                                         \
            _Pragma("unroll")                                                  \
            for (int jm = 0; jm < 4; ++jm)                                     \
                acc[jm][jn] = __builtin_amdgcn_mfma_f32_16x16x32_f16(          \
                    afr[jm], bfr[jn], acc[jm][jn], 0, 0, 0);                   \
        if ((kc_) + 1 < 16) {                                                  \
            WRITEA(wrset_, (buf_) ^ 1);                                        \
            if ((kc_) + 2 < 16)                                                \
                asm volatile("s_waitcnt vmcnt(4) lgkmcnt(0)" ::: "memory");    \
            else                                                               \
                asm volatile("s_waitcnt vmcnt(0) lgkmcnt(0)" ::: "memory");    \
            __builtin_amdgcn_s_barrier();                                      \
        }                                                                      \
    }

    for (int kp = 0; kp < 8; ++kp) {
        STEP(2 * kp,     0, aA, aB);
        STEP(2 * kp + 1, 1, aB, aA);
    }

    // ---- epilogue: rowsum over this wave's 64 n-cols, atomicAdd to scores ----
    const float* avb = addv + b * DH;
    float rowsum[4][4] = {{0.f,0.f,0.f,0.f},{0.f,0.f,0.f,0.f},
                          {0.f,0.f,0.f,0.f},{0.f,0.f,0.f,0.f}};
#pragma unroll
    for (int jn = 0; jn < 4; ++jn) {
        int n = n0 + (ng * 4 + jn) * 16 + l15;
        float av = avb[n];
        float vv = v[n];
#pragma unroll
        for (int jm = 0; jm < 4; ++jm)
#pragma unroll
            for (int r = 0; r < 4; ++r)
                rowsum[jm][r] += vv * fast_tanh(acc[jm][jn][r] + av);
    }
#pragma unroll
    for (int jm = 0; jm < 4; ++jm)
#pragma unroll
        for (int r = 0; r < 4; ++r) {
            float s = rowsum[jm][r];
            s += __shfl_xor(s, 1, 16);
            s += __shfl_xor(s, 2, 16);
            s += __shfl_xor(s, 4, 16);
            s += __shfl_xor(s, 8, 16);
            if (l15 == 0) {
                int srow = s0 + (sg * 4 + jm) * 16 + q * 4 + r;  // C row=q*4+r
                atomicAdd(&scores[b * S_ + srow], s);
            }
        }
}

// ---------------- attn write + sparse weighted context sum (stats fused) ----
__global__ __launch_bounds__(256)
void attnwsum_kernel(const float* __restrict__ scores,
                     const float* __restrict__ context,
                     const void* __restrict__ mask,
                     const int* __restrict__ maskflag,
                     float* __restrict__ attn,
                     float* __restrict__ wsum) {
    __shared__ float rbuf[8];
    __shared__ int   selIdx[64];
    __shared__ float selW[64];
    __shared__ int   selCount;

    int b  = blockIdx.x >> 6;
    int c0 = (blockIdx.x & 63) * 64;
    int tid = threadIdx.x;
    int wv = tid >> 6, ln = tid & 63;
    int isByte = maskflag[0];
    const float* sr = scores + b * S_;

    float mx = -__builtin_inff();
    float vals[16];
#pragma unroll
    for (int it = 0; it < 16; ++it) {
        int s = it * 256 + tid;
        float x = mask_at(mask, isByte, b * S_ + s) ? -__builtin_inff() : sr[s];
        vals[it] = x;
        mx = fmaxf(mx, x);
    }
    for (int o = 1; o < 64; o <<= 1) mx = fmaxf(mx, __shfl_xor(mx, o, 64));
    if (ln == 0) rbuf[wv] = mx;
    __syncthreads();
    mx = fmaxf(fmaxf(rbuf[0], rbuf[1]), fmaxf(rbuf[2], rbuf[3]));

    float sum = 0.f;
#pragma unroll
    for (int it = 0; it < 16; ++it) sum += __expf(vals[it] - mx);
    for (int o = 1; o < 64; o <<= 1) sum += __shfl_xor(sum, o, 64);
    if (ln == 0) rbuf[4 + wv] = sum;
    if (tid == 0) selCount = 0;
    __syncthreads();
    float inv = 1.f / (rbuf[4] + rbuf[5] + rbuf[6] + rbuf[7]);

    if (tid < 64) {
        int s = c0 + tid;
        int idx = b * S_ + s;
        float sc = mask_at(mask, isByte, idx) ? -__builtin_inff() : sr[s];
        float p = __expf(sc - mx) * inv;
        attn[idx] = p;
        if (p > 1e-9f) {
            int k = atomicAdd(&selCount, 1);
            selIdx[k] = s;
            selW[k]  = p;
        }
    }
    __syncthreads();

    int cnt = selCount;
    if (cnt == 0) return;
    const float* cb = context + (size_t)b * S_ * DIN;
    float a00 = 0.f, a01 = 0.f, a10 = 0.f, a11 = 0.f;
    float a20 = 0.f, a21 = 0.f, a30 = 0.f, a31 = 0.f;
    int i = 0;
    for (; i + 4 <= cnt; i += 4) {
        const float* c0p = cb + (size_t)selIdx[i]     * DIN;
        const float* c1p = cb + (size_t)selIdx[i + 1] * DIN;
        const float* c2p = cb + (size_t)selIdx[i + 2] * DIN;
        const float* c3p = cb + (size_t)selIdx[i + 3] * DIN;
        float w0 = selW[i], w1 = selW[i + 1], w2 = selW[i + 2], w3 = selW[i + 3];
        a00 += w0 * c0p[tid]; a01 += w0 * c0p[tid + 256];
        a10 += w1 * c1p[tid]; a11 += w1 * c1p[tid + 256];
        a20 += w2 * c2p[tid]; a21 += w2 * c2p[tid + 256];
        a30 += w3 * c3p[tid]; a31 += w3 * c3p[tid + 256];
    }
    float acc0 = (a00 + a10) + (a20 + a30);
    float acc1 = (a01 + a11) + (a21 + a31);
    for (; i < cnt; ++i) {
        const float* cr = cb + (size_t)selIdx[i] * DIN;
        float w = selW[i];
        acc0 += w * cr[tid];
        acc1 += w * cr[tid + 256];
    }
    atomicAdd(&wsum[b * DIN + tid], acc0);
    atomicAdd(&wsum[b * DIN + tid + 256], acc1);
}

// ---------------- hidden = W_ctx @ wsum + b_ctx ----------------
__global__ __launch_bounds__(256)
void hidden_kernel(const float* __restrict__ W_ctx,
                   const float* __restrict__ b_ctx,
                   const float* __restrict__ wsum,
                   float* __restrict__ hidden) {
    int b = blockIdx.x >> 1;
    int tid = threadIdx.x;
    int h = ((blockIdx.x & 1) << 8) + tid;
    __shared__ float wrow[DIN];
    wrow[tid]       = wsum[b * DIN + tid];
    wrow[tid + 256] = wsum[b * DIN + tid + 256];
    __syncthreads();
    const float* wr = W_ctx + (size_t)h * DIN;
    float acc = 0.f;
    for (int k = 0; k < DIN; k += 4) {
        float4 w4 = *(const float4*)(wr + k);
        acc += w4.x * wrow[k] + w4.y * wrow[k + 1]
             + w4.z * wrow[k + 2] + w4.w * wrow[k + 3];
    }
    hidden[b * DH + h] = acc + b_ctx[h];
}

extern "C" void kernel_launch(void* const* d_in, const int* in_sizes, int n_in,
                              void* d_out, int out_size, void* d_ws, size_t ws_size,
                              hipStream_t stream) {
    const float* input   = (const float*)d_in[0];
    const float* context = (const float*)d_in[1];
    const void*  mask    = d_in[2];
    const float* W_in    = (const float*)d_in[3];
    const float* b_in    = (const float*)d_in[4];
    const float* W_ctx   = (const float*)d_in[5];
    const float* b_ctx   = (const float*)d_in[6];
    const float* v       = (const float*)d_in[7];

    char* ws = (char*)d_ws;
    _Float16* W16   = (_Float16*)ws;
    float* addv     = (float*)(ws + 524288);
    float* scores   = (float*)(ws + 557056);
    float* wsum     = (float*)(ws + 819200);
    int*   maskflag = (int*)(ws + 851968);

    float* hidden = (float*)d_out;                  // [16,512]
    float* attn   = (float*)d_out + B_ * DH;        // [16,4096]

    prep_kernel<<<307, 256, 0, stream>>>(input, W_in, b_in, W_ctx, b_ctx, mask,
                                         W16, addv, scores /*zero region*/,
                                         maskflag);
    score_kernel<<<2048, 256, 0, stream>>>(context, W16, addv, v, scores);
    attnwsum_kernel<<<B_ * 64, 256, 0, stream>>>(scores, context, mask, maskflag,
                                                 attn, wsum);
    hidden_kernel<<<B_ * 2, 256, 0, stream>>>(W_ctx, b_ctx, wsum, hidden);
}

// Round 6
// 290.352 us; speedup vs baseline: 1.1046x; 1.1046x over previous
//
#include <hip/hip_runtime.h>
#include <hip/hip_bf16.h>

#define B_  16
#define S_  4096
#define DIN 512
#define DH  512

typedef _Float16 f16x8 __attribute__((ext_vector_type(8)));
typedef float    f32x4 __attribute__((ext_vector_type(4)));

// ---------------- ws layout (bytes) ----------------
// W16     : [DH][DIN] fp16      @ 0        (524288)
// addv    : [B_][DH]  f32       @ 524288   (32768)   = input@W_in.T + b_in + b_ctx
// scores  : [B_][S_]  f32       @ 557056   (262144)  pure-store by score (no zeroing)
// wsum    : [B_][DIN] f32       @ 819200   (32768)   zeroed in prep, atomicAdd by attnwsum
// maskflag: int                 @ 851968   (4)

__device__ __forceinline__ float fast_tanh(float x) {
    float e = __expf(2.f * x);
    return 1.f - 2.f * __builtin_amdgcn_rcpf(e + 1.f);
}

__device__ __forceinline__ void gload_lds16(const void* g, void* l) {
    __builtin_amdgcn_global_load_lds(
        (const __attribute__((address_space(1))) void*)g,
        (__attribute__((address_space(3))) void*)l, 16, 0, 0);
}

__device__ __forceinline__ int mask_at(const void* mask, int isByte, int idx) {
    return isByte ? (int)((const unsigned char*)mask)[idx]
                  : ((const int*)mask)[idx];
}

// ---------------- prep ----------------
// grid 291:
//   [0,256)   W_ctx f32 -> f16
//   [256,288) addv = input@W_in.T + b_in + b_ctx
//   288       mask dtype detect
//   [289,291) zero wsum (8192 floats)
__global__ __launch_bounds__(256)
void prep_kernel(const float* __restrict__ input,
                 const float* __restrict__ W_in,
                 const float* __restrict__ b_in,
                 const float* __restrict__ W_ctx,
                 const float* __restrict__ b_ctx,
                 const void*  __restrict__ mask,
                 _Float16* __restrict__ W16,
                 float* __restrict__ addv,
                 float* __restrict__ wsum,
                 int* __restrict__ maskflag) {
    int blk = blockIdx.x;
    int tid = threadIdx.x;
    if (blk < 256) {
        int base = blk * 1024 + tid * 4;
        float4 wv = *(const float4*)(W_ctx + base);
        union { _Float16 f[4]; ushort4 u; } cv;
        cv.f[0] = (_Float16)wv.x; cv.f[1] = (_Float16)wv.y;
        cv.f[2] = (_Float16)wv.z; cv.f[3] = (_Float16)wv.w;
        *(ushort4*)(W16 + base) = cv.u;
    } else if (blk < 288) {
        int t = blk - 256;
        int b = t >> 1;
        int h = ((t & 1) << 8) + tid;
        __shared__ float inrow[DIN];
        inrow[tid]       = input[b * DIN + tid];
        inrow[tid + 256] = input[b * DIN + tid + 256];
        __syncthreads();
        const float* wr = W_in + (size_t)h * DIN;
        float acc = 0.f;
        for (int k = 0; k < DIN; k += 4) {
            float4 w4 = *(const float4*)(wr + k);
            acc += w4.x * inrow[k] + w4.y * inrow[k + 1]
                 + w4.z * inrow[k + 2] + w4.w * inrow[k + 3];
        }
        addv[b * DH + h] = acc + b_in[h] + b_ctx[h];
    } else if (blk == 288) {
        const uint4* m4 = (const uint4*)mask;
        unsigned int orw = 0;
#pragma unroll
        for (int it = 0; it < 16; ++it) {
            uint4 w = m4[it * 256 + tid];
            orw |= (w.x | w.y | w.z | w.w);
        }
        int found = ((orw & 0xFFFFFF00u) != 0) ? 1 : 0;
        __shared__ int f;
        if (tid == 0) f = 0;
        __syncthreads();
        if (found) atomicOr(&f, 1);
        __syncthreads();
        if (tid == 0) maskflag[0] = f;
    } else {
        int base = (blk - 289) * 4096;
#pragma unroll
        for (int it = 0; it < 16; ++it)
            wsum[base + it * 256 + tid] = 0.f;
    }
}

// ---------------- score GEMM: scores = rowsum of v.tanh(addv + ctx@W16^T) ----
// One block per (b, 128-row s-chunk) covering ALL 512 n-cols (nt=1):
//   - fused ctx f32->f16 conversion is ZERO-redundancy (panel owned by 1 block)
//   - grid 512 = exactly 2 blocks/CU, ONE dispatch round; co-resident pair
//     mutually hides barrier drains
//   - B (W16, 0.5MB, L2-resident) via global_load_lds width-16, 4/thread/step
//   - A reg-staged (r4's verified linear mapping, 0 bank conflicts), 2-deep
//     named lookahead, plain __syncthreads() (r5 showed hand-vmcnt regresses)
//   - 512 thr / 8 waves (2sg x 4ng), wave tile 64x128, acc[4][8],
//     32 MFMA/wave/step (2x r4's density per barrier)
//   - epilogue: LDS reduce across the 4 ng-waves -> PURE STORE of scores
//     (no pre-zero, no atomics)
// LDS: As 2x8KB + Bs 2x32KB = exactly 80KB -> 2 blocks/CU.
__global__ __launch_bounds__(512, 1)
void score_kernel(const float* __restrict__ context,
                  const _Float16* __restrict__ W16,
                  const float* __restrict__ addv,
                  const float* __restrict__ v,
                  float* __restrict__ scores) {
    __shared__ __align__(16) _Float16 As[2][4096];    // 8KB/buf: 8 m-tiles
    __shared__ __align__(16) _Float16 Bs[2][16384];   // 32KB/buf: 32 n-tiles

    const int tid  = threadIdx.x;
    const int wave = tid >> 6;
    const int lane = tid & 63;
    const int l15  = lane & 15;
    const int q    = lane >> 4;
    const int sg   = wave >> 2;        // 0..1 : s-group (64 rows)
    const int ng   = wave & 3;         // 0..3 : n-group (128 cols)

    const int b  = blockIdx.x >> 5;
    const int st = blockIdx.x & 31;
    const int s0 = st * 128;

    const float* ctxA = context + ((size_t)b * S_ + s0) * DIN;

    // A ownership (verified linear mapping): tid*8 = mtile*512 + q16*128 + r*8
    //   mtile=tid>>6, q16=(tid>>4)&3, r=tid&15 -> row=mtile*16+r, kb=q16*8.
    // Thread loads 8 f32 from ctxA[row*DIN + kc*32 + kb], writes f16x8 at
    // As halves tid*8 (strictly linear 16B/lane => 0 bank conflicts).
    const int rowA = ((tid >> 6) * 16) + (tid & 15);
    const int kbA  = ((tid >> 4) & 3) * 8;

    // B stage: 32 n-tiles (16 rows x 32 halves = 1KB each), 4 per wave.
    // lane L -> row jn*16+l15, k kc*32+q*8 ; lands at Bs[jn*512 + L*8].
#define STAGE_B(kc_, buf_)                                                     \
    {                                                                          \
        _Pragma("unroll")                                                      \
        for (int u = 0; u < 4; ++u) {                                          \
            int jn = wave * 4 + u;                                             \
            const _Float16* gp = W16 +                                         \
                (size_t)(jn * 16 + l15) * DIN + (kc_) * 32 + q * 8;            \
            gload_lds16(gp, &Bs[buf_][jn * 512]);                              \
        }                                                                      \
    }

#define LOADA(kc_, set_)                                                       \
    {                                                                          \
        const float* g0 = ctxA + (size_t)rowA * DIN + (kc_) * 32 + kbA;        \
        set_[0] = *(const float4*)g0;                                          \
        set_[1] = *(const float4*)(g0 + 4);                                    \
    }

#define WRITEA(set_, buf_)                                                     \
    {                                                                          \
        f16x8 h0;                                                              \
        h0[0] = (_Float16)set_[0].x; h0[1] = (_Float16)set_[0].y;              \
        h0[2] = (_Float16)set_[0].z; h0[3] = (_Float16)set_[0].w;              \
        h0[4] = (_Float16)set_[1].x; h0[5] = (_Float16)set_[1].y;              \
        h0[6] = (_Float16)set_[1].z; h0[7] = (_Float16)set_[1].w;              \
        *(f16x8*)&As[buf_][tid * 8] = h0;                                      \
    }

    f32x4 acc[4][8];
#pragma unroll
    for (int jm = 0; jm < 4; ++jm)
#pragma unroll
        for (int jn = 0; jn < 8; ++jn) acc[jm][jn] = (f32x4){0.f, 0.f, 0.f, 0.f};

    float4 aA[2], aB[2];   // two named lookahead sets (rule-#20-safe)

    // prologue
    STAGE_B(0, 0);
    LOADA(0, aA);
    WRITEA(aA, 0);
    LOADA(1, aB);
    __syncthreads();

#define STEP(kc_, buf_, ldset_, wrset_)                                        \
    {                                                                          \
        if ((kc_) + 1 < 16) STAGE_B((kc_) + 1, (buf_) ^ 1);                    \
        if ((kc_) + 2 < 16) LOADA((kc_) + 2, ldset_);                          \
        f16x8 afr[4], bfr[8];                                                  \
        _Pragma("unroll")                                                      \
        for (int jm = 0; jm < 4; ++jm)                                         \
            afr[jm] = *(const f16x8*)&As[buf_][(sg * 4 + jm) * 512 +           \
                                              q * 128 + l15 * 8];              \
        _Pragma("unroll")                                                      \
        for (int jn = 0; jn < 8; ++jn)                                         \
            bfr[jn] = *(const f16x8*)&Bs[buf_][(ng * 8 + jn) * 512 +           \
                                              q * 128 + l15 * 8];              \
        _Pragma("unroll")                                                      \
        for (int jn = 0; jn < 8; ++jn)                                         \
            _Pragma("unroll")                                                  \
            for (int jm = 0; jm < 4; ++jm)                                     \
                acc[jm][jn] = __builtin_amdgcn_mfma_f32_16x16x32_f16(          \
                    afr[jm], bfr[jn], acc[jm][jn], 0, 0, 0);                   \
        if ((kc_) + 1 < 16) WRITEA(wrset_, (buf_) ^ 1);                        \
        __syncthreads();                                                       \
    }

    for (int kp = 0; kp < 8; ++kp) {
        STEP(2 * kp,     0, aA, aB);
        STEP(2 * kp + 1, 1, aB, aA);
    }

    // ---- epilogue: rowsum over this wave's 128 n-cols, LDS-reduce over ng ----
    const float* avb = addv + b * DH;
    float rowsum[4][4] = {{0.f,0.f,0.f,0.f},{0.f,0.f,0.f,0.f},
                          {0.f,0.f,0.f,0.f},{0.f,0.f,0.f,0.f}};
#pragma unroll
    for (int jn = 0; jn < 8; ++jn) {
        int n = (ng * 8 + jn) * 16 + l15;
        float av = avb[n];
        float vv = v[n];
#pragma unroll
        for (int jm = 0; jm < 4; ++jm)
#pragma unroll
            for (int r = 0; r < 4; ++r)
                rowsum[jm][r] += vv * fast_tanh(acc[jm][jn][r] + av);
    }
    // sred[ng][128] overlaid on As[0] (free after last step; all waves passed
    // the final __syncthreads)
    float* sredF = (float*)&As[0][0];
#pragma unroll
    for (int jm = 0; jm < 4; ++jm)
#pragma unroll
        for (int r = 0; r < 4; ++r) {
            float s = rowsum[jm][r];
            s += __shfl_xor(s, 1, 16);
            s += __shfl_xor(s, 2, 16);
            s += __shfl_xor(s, 4, 16);
            s += __shfl_xor(s, 8, 16);
            if (l15 == 0) {
                int rowL = (sg * 4 + jm) * 16 + q * 4 + r;   // 0..127
                sredF[ng * 128 + rowL] = s;
            }
        }
    __syncthreads();
    if (tid < 128) {
        float out = sredF[tid] + sredF[128 + tid] +
                    sredF[256 + tid] + sredF[384 + tid];
        scores[b * S_ + s0 + tid] = out;
    }
}

// ---------------- attn write + sparse weighted context sum (stats fused) ----
__global__ __launch_bounds__(256)
void attnwsum_kernel(const float* __restrict__ scores,
                     const float* __restrict__ context,
                     const void* __restrict__ mask,
                     const int* __restrict__ maskflag,
                     float* __restrict__ attn,
                     float* __restrict__ wsum) {
    __shared__ float rbuf[8];
    __shared__ int   selIdx[64];
    __shared__ float selW[64];
    __shared__ int   selCount;

    int b  = blockIdx.x >> 6;
    int c0 = (blockIdx.x & 63) * 64;
    int tid = threadIdx.x;
    int wv = tid >> 6, ln = tid & 63;
    int isByte = maskflag[0];
    const float* sr = scores + b * S_;

    float mx = -__builtin_inff();
    float vals[16];
#pragma unroll
    for (int it = 0; it < 16; ++it) {
        int s = it * 256 + tid;
        float x = mask_at(mask, isByte, b * S_ + s) ? -__builtin_inff() : sr[s];
        vals[it] = x;
        mx = fmaxf(mx, x);
    }
    for (int o = 1; o < 64; o <<= 1) mx = fmaxf(mx, __shfl_xor(mx, o, 64));
    if (ln == 0) rbuf[wv] = mx;
    __syncthreads();
    mx = fmaxf(fmaxf(rbuf[0], rbuf[1]), fmaxf(rbuf[2], rbuf[3]));

    float sum = 0.f;
#pragma unroll
    for (int it = 0; it < 16; ++it) sum += __expf(vals[it] - mx);
    for (int o = 1; o < 64; o <<= 1) sum += __shfl_xor(sum, o, 64);
    if (ln == 0) rbuf[4 + wv] = sum;
    if (tid == 0) selCount = 0;
    __syncthreads();
    float inv = 1.f / (rbuf[4] + rbuf[5] + rbuf[6] + rbuf[7]);

    if (tid < 64) {
        int s = c0 + tid;
        int idx = b * S_ + s;
        float sc = mask_at(mask, isByte, idx) ? -__builtin_inff() : sr[s];
        float p = __expf(sc - mx) * inv;
        attn[idx] = p;
        if (p > 1e-9f) {
            int k = atomicAdd(&selCount, 1);
            selIdx[k] = s;
            selW[k]  = p;
        }
    }
    __syncthreads();

    int cnt = selCount;
    if (cnt == 0) return;
    const float* cb = context + (size_t)b * S_ * DIN;
    float a00 = 0.f, a01 = 0.f, a10 = 0.f, a11 = 0.f;
    float a20 = 0.f, a21 = 0.f, a30 = 0.f, a31 = 0.f;
    int i = 0;
    for (; i + 4 <= cnt; i += 4) {
        const float* c0p = cb + (size_t)selIdx[i]     * DIN;
        const float* c1p = cb + (size_t)selIdx[i + 1] * DIN;
        const float* c2p = cb + (size_t)selIdx[i + 2] * DIN;
        const float* c3p = cb + (size_t)selIdx[i + 3] * DIN;
        float w0 = selW[i], w1 = selW[i + 1], w2 = selW[i + 2], w3 = selW[i + 3];
        a00 += w0 * c0p[tid]; a01 += w0 * c0p[tid + 256];
        a10 += w1 * c1p[tid]; a11 += w1 * c1p[tid + 256];
        a20 += w2 * c2p[tid]; a21 += w2 * c2p[tid + 256];
        a30 += w3 * c3p[tid]; a31 += w3 * c3p[tid + 256];
    }
    float acc0 = (a00 + a10) + (a20 + a30);
    float acc1 = (a01 + a11) + (a21 + a31);
    for (; i < cnt; ++i) {
        const float* cr = cb + (size_t)selIdx[i] * DIN;
        float w = selW[i];
        acc0 += w * cr[tid];
        acc1 += w * cr[tid + 256];
    }
    atomicAdd(&wsum[b * DIN + tid], acc0);
    atomicAdd(&wsum[b * DIN + tid + 256], acc1);
}

// ---------------- hidden = W_ctx @ wsum + b_ctx ----------------
__global__ __launch_bounds__(256)
void hidden_kernel(const float* __restrict__ W_ctx,
                   const float* __restrict__ b_ctx,
                   const float* __restrict__ wsum,
                   float* __restrict__ hidden) {
    int b = blockIdx.x >> 1;
    int tid = threadIdx.x;
    int h = ((blockIdx.x & 1) << 8) + tid;
    __shared__ float wrow[DIN];
    wrow[tid]       = wsum[b * DIN + tid];
    wrow[tid + 256] = wsum[b * DIN + tid + 256];
    __syncthreads();
    const float* wr = W_ctx + (size_t)h * DIN;
    float acc = 0.f;
    for (int k = 0; k < DIN; k += 4) {
        float4 w4 = *(const float4*)(wr + k);
        acc += w4.x * wrow[k] + w4.y * wrow[k + 1]
             + w4.z * wrow[k + 2] + w4.w * wrow[k + 3];
    }
    hidden[b * DH + h] = acc + b_ctx[h];
}

extern "C" void kernel_launch(void* const* d_in, const int* in_sizes, int n_in,
                              void* d_out, int out_size, void* d_ws, size_t ws_size,
                              hipStream_t stream) {
    const float* input   = (const float*)d_in[0];
    const float* context = (const float*)d_in[1];
    const void*  mask    = d_in[2];
    const float* W_in    = (const float*)d_in[3];
    const float* b_in    = (const float*)d_in[4];
    const float* W_ctx   = (const float*)d_in[5];
    const float* b_ctx   = (const float*)d_in[6];
    const float* v       = (const float*)d_in[7];

    char* ws = (char*)d_ws;
    _Float16* W16   = (_Float16*)ws;
    float* addv     = (float*)(ws + 524288);
    float* scores   = (float*)(ws + 557056);
    float* wsum     = (float*)(ws + 819200);
    int*   maskflag = (int*)(ws + 851968);

    float* hidden = (float*)d_out;                  // [16,512]
    float* attn   = (float*)d_out + B_ * DH;        // [16,4096]

    prep_kernel<<<291, 256, 0, stream>>>(input, W_in, b_in, W_ctx, b_ctx, mask,
                                         W16, addv, wsum, maskflag);
    score_kernel<<<512, 512, 0, stream>>>(context, W16, addv, v, scores);
    attnwsum_kernel<<<B_ * 64, 256, 0, stream>>>(scores, context, mask, maskflag,
                                                 attn, wsum);
    hidden_kernel<<<B_ * 2, 256, 0, stream>>>(W_ctx, b_ctx, wsum, hidden);
}